// Round 14
// baseline (522.234 us; speedup 1.0000x reference)
//
#include <hip/hip_runtime.h>
#include <hip/hip_bf16.h>
#include <math.h>

#define NTOK 4096   // B*L
#define DM   2048   // model dim
#define NE   8      // experts
#define BK   64

using f32x4  = float __attribute__((ext_vector_type(4)));
using bf16x8 = __bf16 __attribute__((ext_vector_type(8)));
using u32x4  = unsigned int __attribute__((ext_vector_type(4)));

__device__ __forceinline__ unsigned short bf16bits(float f){
  unsigned u = __builtin_bit_cast(unsigned, f);
  return (unsigned short)((u + 0x7fffu + ((u >> 16) & 1u)) >> 16);  // RNE
}

__device__ __forceinline__ void load_lds16(const void* g, void* l){
  __builtin_amdgcn_global_load_lds(
      (const __attribute__((address_space(1))) unsigned int*)g,
      (__attribute__((address_space(3))) unsigned int*)l, 16, 0, 0);
}

// ---------------- router: rms-scale -> logits -> softmax -> top2 -> bucketize; also x->bf16
__global__ __launch_bounds__(256) void router_kernel(
    const float* __restrict__ x, const float* __restrict__ rs,
    const float* __restrict__ gw, const float* __restrict__ pes,
    unsigned short* __restrict__ xbf, int* __restrict__ cnt,
    int* __restrict__ toklist, float* __restrict__ slotw)
{
  const int wv = threadIdx.x >> 6, l = threadIdx.x & 63;
  const int n = blockIdx.x * 4 + wv;            // one wave per token
  const float* xr = x + (size_t)n * DM;
  unsigned short* xb = xbf + (size_t)n * DM;
  float ssq = 0.f;
  float lg[8] = {0,0,0,0,0,0,0,0};
  #pragma unroll
  for (int q = 0; q < 8; ++q){
    int c4 = l + 64 * q;                         // float4 chunk
    float4 v = ((const float4*)xr)[c4];
    float4 r = ((const float4*)rs)[c4];
    ssq += v.x*v.x + v.y*v.y + v.z*v.z + v.w*v.w;
    ushort4 o; o.x = bf16bits(v.x); o.y = bf16bits(v.y); o.z = bf16bits(v.z); o.w = bf16bits(v.w);
    ((ushort4*)xb)[c4] = o;
    float xs0 = v.x*r.x, xs1 = v.y*r.y, xs2 = v.z*r.z, xs3 = v.w*r.w;
    const float4* gp = (const float4*)(gw + (size_t)c4 * 32); // 4 rows x 8 experts
    float4 ga, gb;
    ga = gp[0]; gb = gp[1];
    lg[0]+=xs0*ga.x; lg[1]+=xs0*ga.y; lg[2]+=xs0*ga.z; lg[3]+=xs0*ga.w;
    lg[4]+=xs0*gb.x; lg[5]+=xs0*gb.y; lg[6]+=xs0*gb.z; lg[7]+=xs0*gb.w;
    ga = gp[2]; gb = gp[3];
    lg[0]+=xs1*ga.x; lg[1]+=xs1*ga.y; lg[2]+=xs1*ga.z; lg[3]+=xs1*ga.w;
    lg[4]+=xs1*gb.x; lg[5]+=xs1*gb.y; lg[6]+=xs1*gb.z; lg[7]+=xs1*gb.w;
    ga = gp[4]; gb = gp[5];
    lg[0]+=xs2*ga.x; lg[1]+=xs2*ga.y; lg[2]+=xs2*ga.z; lg[3]+=xs2*ga.w;
    lg[4]+=xs2*gb.x; lg[5]+=xs2*gb.y; lg[6]+=xs2*gb.z; lg[7]+=xs2*gb.w;
    ga = gp[6]; gb = gp[7];
    lg[0]+=xs3*ga.x; lg[1]+=xs3*ga.y; lg[2]+=xs3*ga.z; lg[3]+=xs3*ga.w;
    lg[4]+=xs3*gb.x; lg[5]+=xs3*gb.y; lg[6]+=xs3*gb.z; lg[7]+=xs3*gb.w;
  }
  #pragma unroll
  for (int off = 32; off; off >>= 1){
    ssq += __shfl_xor(ssq, off, 64);
    #pragma unroll
    for (int e2 = 0; e2 < 8; ++e2) lg[e2] += __shfl_xor(lg[e2], off, 64);
  }
  if (l == 0){
    float c = rsqrtf(ssq * (1.0f/DM) + 1e-6f) * 0.022097086912079608f; // rms * D^-0.5
    float mx = -1e30f;
    #pragma unroll
    for (int e2 = 0; e2 < 8; ++e2){ lg[e2] *= c; mx = fmaxf(mx, lg[e2]); }
    float l0 = lg[0]; int i0 = 0;
    #pragma unroll
    for (int e2 = 1; e2 < 8; ++e2) if (lg[e2] > l0){ l0 = lg[e2]; i0 = e2; }
    int i1 = (i0 == 0) ? 1 : 0; float l1 = (i0 == 0) ? lg[1] : lg[0];
    #pragma unroll
    for (int e2 = 0; e2 < 8; ++e2){ if (e2 != i0 && lg[e2] > l1){ l1 = lg[e2]; i1 = e2; } }
    float p0 = expf(l0 - mx), p1 = expf(l1 - mx);
    float sw = fmaxf(p0 + p1, 1e-12f);
    float w0 = p0 / sw, w1 = p1 / sw;
    int s0 = atomicAdd(&cnt[i0], 1);
    toklist[i0 * NTOK + s0] = n;
    slotw[i0 * NTOK + s0] = w0 * pes[i0];
    int s1 = atomicAdd(&cnt[i1], 1);
    toklist[i1 * NTOK + s1] = n;
    slotw[i1 * NTOK + s1] = w1 * pes[i1];
  }
}

__global__ void scan_kernel(const int* __restrict__ cnt, int* __restrict__ basep){
  if (threadIdx.x == 0){
    int a = 0;
    for (int e = 0; e < NE; ++e){ basep[e] = a; a += cnt[e]; }
  }
}

// ---------------- weight convert + transpose: W fp32 [2048 k][ncols n] -> Wt bf16 [ncols n][2048 k]
__global__ __launch_bounds__(256) void conv_transpose_kernel(
    const float* __restrict__ W, unsigned short* __restrict__ Wt, int ncols)
{
  const int z = blockIdx.z;
  const float* src = W + (size_t)z * 2048 * ncols;
  unsigned short* dst = Wt + (size_t)z * ncols * 2048;
  const int n0 = blockIdx.x * 64, k0 = blockIdx.y * 64;
  __shared__ __align__(16) unsigned short t[64][72];
  const int tid = threadIdx.x;
  const int kl = tid >> 4;
  const int nl = (tid & 15) * 4;
  #pragma unroll
  for (int q = 0; q < 4; ++q){
    int k = kl + q * 16;
    float4 v = *(const float4*)(src + (size_t)(k0 + k) * ncols + n0 + nl);
    t[nl+0][k] = bf16bits(v.x);
    t[nl+1][k] = bf16bits(v.y);
    t[nl+2][k] = bf16bits(v.z);
    t[nl+3][k] = bf16bits(v.w);
  }
  __syncthreads();
  const int nr = tid >> 3;
  const int k8 = (tid & 7) * 8;
  #pragma unroll
  for (int q = 0; q < 2; ++q){
    int n = nr + q * 32;
    u32x4 v = *(const u32x4*)&t[n][k8];
    *(u32x4*)(dst + (size_t)(n0 + n) * 2048 + k0 + k8) = v;
  }
}

// ---------------- grouped GEMM, m97 structure: 128-row tiles, BK=64, 4 waves (2x2),
// 32KB LDS single-buffered, global_load_lds both operands, 4 blocks/CU.
// NEW (R13): XCD-pinned schedule -- expert e = flat%8 (dispatch heuristic: XCD =
// flat blockIdx % 8), dense j-packing via Mreal = ceil(cnt/128), m-fastest within
// XCD (consecutive j share a B panel -> W streams through its XCD's L2 exactly once;
// the expert's ~4MB gathered-A stays hot in L2).
// NOTE: bounds MUST be (256,4): acc[4][4] f32x4 = 64 VGPRs; (256,5) spills (R11).
// MODE 0: 64 gate + 64 up cols/block; epilogue gelu(g)*u -> act bf16 directly.
// MODE 1: 128 cols/block; fp32 atomic scatter to out (2 commutative adds/elem).
template<int MODE>
__global__ __launch_bounds__(256, 4) void moe_gemm(
    const unsigned short* __restrict__ Abuf,   // xbf (MODE0) / act (MODE1)
    const unsigned short* __restrict__ Wt,     // bf16 [z][ncols][2048] (group-local)
    unsigned short* __restrict__ act,
    float* __restrict__ out,
    const int* __restrict__ cnt,
    const int* __restrict__ basep,
    const int* __restrict__ toklist,
    const float* __restrict__ slotw,
    int e0)
{
  int e, fbi, m0;
  if (gridDim.z == NE){
    // XCD-pinned remap: e = flat%8; within XCD, m-fastest dense packing.
    int flat = blockIdx.x + gridDim.x * (blockIdx.y + 32 * blockIdx.z);
    e = e0 + (flat & 7);
    int Mreal = (cnt[e] + 127) >> 7;
    int j = flat >> 3;
    if (j >= Mreal * (int)gridDim.x) return;
    m0 = (j % Mreal) * 128;
    fbi = j / Mreal;
  } else {
    e = e0 + blockIdx.z;
    m0 = blockIdx.y * 128;
    fbi = blockIdx.x;
  }
  const int z = e - e0;
  const int ce = cnt[e];
  if (m0 >= ce) return;
  const int tid = threadIdx.x;
  const int l = tid & 63;
  const int wv = tid >> 6;          // 0..3
  const int wr = wv >> 1, wc = wv & 1;
  const int baseE = basep[e];
  const size_t ncols = (MODE == 0) ? 4096 : 2048;
  const unsigned short* Wz = Wt + (size_t)z * ncols * 2048;

  __shared__ __align__(16) unsigned short As[128 * BK];   // 16 KiB
  __shared__ __align__(16) unsigned short Bs[128 * BK];   // 16 KiB
  __shared__ unsigned char diagpad[MODE ? 544 : 16];      // profile marker (33280 vs 32768)
  if (basep[0] == -1) *(volatile unsigned char*)&diagpad[tid & 15] = 1;  // never true

  // staging: chunk c = q*256+tid -> row = q*32 + (tid>>3), phys granule tid&7,
  // logical granule g = (tid&7) ^ (row&7); LDS dst linear (wave-uniform base + lane*16B)
  const unsigned short* asrc[4];
  const unsigned short* bsrc[4];
  #pragma unroll
  for (int q = 0; q < 4; ++q){
    int row = q * 32 + (tid >> 3);
    int g = (tid & 7) ^ (row & 7);
    long rs;
    if (MODE == 0) rs = toklist[e * NTOK + min(m0 + row, ce - 1)];
    else           rs = baseE + min(m0 + row, ce - 1);
    asrc[q] = Abuf + (size_t)rs * 2048 + g * 8;
    int wcol;
    if (MODE == 0) wcol = (row < 64) ? (fbi * 64 + row) : (2048 + fbi * 64 + row - 64);
    else           wcol = fbi * 128 + row;
    bsrc[q] = Wz + (size_t)wcol * 2048 + g * 8;
  }

  f32x4 acc[4][4];
  #pragma unroll
  for (int i = 0; i < 4; ++i)
    #pragma unroll
    for (int j2 = 0; j2 < 4; ++j2)
      acc[i][j2] = (f32x4){0.f, 0.f, 0.f, 0.f};

  const int aoff0 = (wr * 64 + (l & 15)) * BK;
  int boffs[4];
  if (MODE == 0){
    // ni 0,1 = gate cols (Bs 0..63), ni 2,3 = up cols (Bs 64..127); same lane-col pairing
    boffs[0] = (wc * 32 + (l & 15)) * BK;
    boffs[1] = (wc * 32 + 16 + (l & 15)) * BK;
    boffs[2] = (64 + wc * 32 + (l & 15)) * BK;
    boffs[3] = (64 + wc * 32 + 16 + (l & 15)) * BK;
  } else {
    #pragma unroll
    for (int ni = 0; ni < 4; ++ni) boffs[ni] = (wc * 64 + ni * 16 + (l & 15)) * BK;
  }
  const int lsw = l & 7;
  const int lq = l >> 4;

  #pragma unroll 1
  for (int k0 = 0; k0 < 2048; k0 += BK){
    if (k0) __syncthreads();
    #pragma unroll
    for (int q = 0; q < 4; ++q)
      load_lds16(asrc[q] + k0, &As[q * 2048 + wv * 512]);
    #pragma unroll
    for (int q = 0; q < 4; ++q)
      load_lds16(bsrc[q] + k0, &Bs[q * 2048 + wv * 512]);
    __syncthreads();
    #pragma unroll
    for (int kk = 0; kk < 2; ++kk){
      const int gsw = ((kk * 4 + lq) ^ lsw) * 8;
      bf16x8 af[4];
      #pragma unroll
      for (int mi = 0; mi < 4; ++mi)
        af[mi] = *(const bf16x8*)&As[aoff0 + mi * 16 * BK + gsw];
      #pragma unroll
      for (int ni = 0; ni < 4; ++ni){
        bf16x8 bfr = *(const bf16x8*)&Bs[boffs[ni] + gsw];
        #pragma unroll
        for (int mi = 0; mi < 4; ++mi)
          acc[mi][ni] = __builtin_amdgcn_mfma_f32_16x16x32_bf16(
              af[mi], bfr, acc[mi][ni], 0, 0, 0);
      }
    }
  }

  const int lq4 = (l >> 4) * 4;
  if (MODE == 0){
    #pragma unroll
    for (int mi = 0; mi < 4; ++mi)
      #pragma unroll
      for (int j2 = 0; j2 < 4; ++j2){
        int s = m0 + wr * 64 + mi * 16 + lq4 + j2;
        if (s < ce){
          size_t rowb = (size_t)(baseE + s) * 2048;
          #pragma unroll
          for (int p = 0; p < 2; ++p){
            float g = acc[mi][p][j2];
            float u = acc[mi][p + 2][j2];
            float a = 0.5f * g * (1.0f + erff(g * 0.70710678118654752f)) * u; // exact gelu*up
            act[rowb + fbi * 64 + wc * 32 + p * 16 + (l & 15)] = bf16bits(a);
          }
        }
      }
  } else {
    #pragma unroll
    for (int mi = 0; mi < 4; ++mi)
      #pragma unroll
      for (int j2 = 0; j2 < 4; ++j2){
        int s = m0 + wr * 64 + mi * 16 + lq4 + j2;
        if (s < ce){
          int tokn = toklist[e * NTOK + s];
          float wgt = slotw[e * NTOK + s];
          float* orow = out + (size_t)tokn * 2048 + fbi * 128 + wc * 64 + (l & 15);
          #pragma unroll
          for (int ni = 0; ni < 4; ++ni)
            atomicAdd(&orow[ni * 16], wgt * acc[mi][ni][j2]);
        }
      }
  }
}

extern "C" void kernel_launch(void* const* d_in, const int* in_sizes, int n_in,
                              void* d_out, int out_size, void* d_ws, size_t ws_size,
                              hipStream_t stream)
{
  const float* x   = (const float*)d_in[0];
  const float* rs  = (const float*)d_in[1];
  const float* gw  = (const float*)d_in[2];
  const float* w1  = (const float*)d_in[3];
  const float* w2  = (const float*)d_in[4];
  const float* pes = (const float*)d_in[5];
  float* out = (float*)d_out;

  // ws: cnt | base | toklist(128K) | slotw(128K) | xbf 16MB | act 32MB | Wt region
  char* ws = (char*)d_ws;
  int*   cnt      = (int*)ws;
  int*   basep    = (int*)(ws + 64);
  int*   toklist  = (int*)(ws + 256);
  float* slotw    = (float*)(ws + 256 + (size_t)NE * NTOK * 4);
  unsigned short* xbf  = (unsigned short*)(ws + 256 + 2 * (size_t)NE * NTOK * 4);
  unsigned short* act  = xbf + (size_t)NTOK * DM;
  unsigned short* wtb  = act + (size_t)2 * NTOK * DM;

  const size_t fixed = (size_t)((char*)wtb - ws);       // ~48.3 MiB
  const size_t per_e = (size_t)4096 * 2048 * 2;         // 16 MiB (W1; W2 uses half)

  hipMemsetAsync(out, 0, (size_t)out_size * sizeof(float), stream);
  hipMemsetAsync(cnt, 0, 64, stream);
  router_kernel<<<NTOK / 4, 256, 0, stream>>>(x, rs, gw, pes, xbf, cnt, toklist, slotw);
  scan_kernel<<<1, 64, 0, stream>>>(cnt, basep);

  if (ws_size >= fixed + (size_t)NE * per_e){
    // single-pass path: all 8 experts per conv/gemm (established: ws >= 176.3 MiB)
    conv_transpose_kernel<<<dim3(64, 32, NE), 256, 0, stream>>>(w1, wtb, 4096);
    moe_gemm<0><<<dim3(32, 32, NE), 256, 0, stream>>>(
        xbf, wtb, act, out, cnt, basep, toklist, slotw, 0);
    conv_transpose_kernel<<<dim3(32, 32, NE), 256, 0, stream>>>(w2, wtb, 2048);
    moe_gemm<1><<<dim3(16, 32, NE), 256, 0, stream>>>(
        act, wtb, act, out, cnt, basep, toklist, slotw, 0);
  } else {
    int EG = (int)((ws_size > fixed) ? ((ws_size - fixed) / per_e) : 0);
    if (EG < 1) EG = 1;
    if (EG > NE) EG = NE;
    for (int g = 0; g < NE; g += EG){
      int gg = min(EG, NE - g);
      conv_transpose_kernel<<<dim3(64, 32, gg), 256, 0, stream>>>(
          w1 + (size_t)g * 2048 * 4096, wtb, 4096);
      moe_gemm<0><<<dim3(32, 32, gg), 256, 0, stream>>>(
          xbf, wtb, act, out, cnt, basep, toklist, slotw, g);
    }
    for (int g = 0; g < NE; g += EG){
      int gg = min(EG, NE - g);
      conv_transpose_kernel<<<dim3(32, 32, gg), 256, 0, stream>>>(
          w2 + (size_t)g * 2048 * 2048, wtb, 2048);
      moe_gemm<1><<<dim3(16, 32, gg), 256, 0, stream>>>(
          act, wtb, act, out, cnt, basep, toklist, slotw, g);
    }
  }
}

// Round 15
// 485.286 us; speedup vs baseline: 1.0761x; 1.0761x over previous
//
#include <hip/hip_runtime.h>
#include <hip/hip_bf16.h>
#include <math.h>

#define NTOK 4096   // B*L
#define DM   2048   // model dim
#define NE   8      // experts
#define BK   64

using f32x4  = float __attribute__((ext_vector_type(4)));
using bf16x8 = __bf16 __attribute__((ext_vector_type(8)));
using u32x4  = unsigned int __attribute__((ext_vector_type(4)));

__device__ __forceinline__ unsigned short bf16bits(float f){
  unsigned u = __builtin_bit_cast(unsigned, f);
  return (unsigned short)((u + 0x7fffu + ((u >> 16) & 1u)) >> 16);  // RNE
}

__device__ __forceinline__ float bflo(unsigned u){ return __builtin_bit_cast(float, u << 16); }
__device__ __forceinline__ float bfhi(unsigned u){ return __builtin_bit_cast(float, u & 0xffff0000u); }

__device__ __forceinline__ void load_lds16(const void* g, void* l){
  __builtin_amdgcn_global_load_lds(
      (const __attribute__((address_space(1))) unsigned int*)g,
      (__attribute__((address_space(3))) unsigned int*)l, 16, 0, 0);
}

// ---------------- router: rms-scale -> logits -> softmax -> top2 -> bucketize; also x->bf16
__global__ __launch_bounds__(256) void router_kernel(
    const float* __restrict__ x, const float* __restrict__ rs,
    const float* __restrict__ gw, const float* __restrict__ pes,
    unsigned short* __restrict__ xbf, int* __restrict__ cnt,
    int* __restrict__ toklist, float* __restrict__ slotw,
    int* __restrict__ tok2slot)
{
  const int wv = threadIdx.x >> 6, l = threadIdx.x & 63;
  const int n = blockIdx.x * 4 + wv;            // one wave per token
  const float* xr = x + (size_t)n * DM;
  unsigned short* xb = xbf + (size_t)n * DM;
  float ssq = 0.f;
  float lg[8] = {0,0,0,0,0,0,0,0};
  #pragma unroll
  for (int q = 0; q < 8; ++q){
    int c4 = l + 64 * q;                         // float4 chunk
    float4 v = ((const float4*)xr)[c4];
    float4 r = ((const float4*)rs)[c4];
    ssq += v.x*v.x + v.y*v.y + v.z*v.z + v.w*v.w;
    ushort4 o; o.x = bf16bits(v.x); o.y = bf16bits(v.y); o.z = bf16bits(v.z); o.w = bf16bits(v.w);
    ((ushort4*)xb)[c4] = o;
    float xs0 = v.x*r.x, xs1 = v.y*r.y, xs2 = v.z*r.z, xs3 = v.w*r.w;
    const float4* gp = (const float4*)(gw + (size_t)c4 * 32); // 4 rows x 8 experts
    float4 ga, gb;
    ga = gp[0]; gb = gp[1];
    lg[0]+=xs0*ga.x; lg[1]+=xs0*ga.y; lg[2]+=xs0*ga.z; lg[3]+=xs0*ga.w;
    lg[4]+=xs0*gb.x; lg[5]+=xs0*gb.y; lg[6]+=xs0*gb.z; lg[7]+=xs0*gb.w;
    ga = gp[2]; gb = gp[3];
    lg[0]+=xs1*ga.x; lg[1]+=xs1*ga.y; lg[2]+=xs1*ga.z; lg[3]+=xs1*ga.w;
    lg[4]+=xs1*gb.x; lg[5]+=xs1*gb.y; lg[6]+=xs1*gb.z; lg[7]+=xs1*gb.w;
    ga = gp[4]; gb = gp[5];
    lg[0]+=xs2*ga.x; lg[1]+=xs2*ga.y; lg[2]+=xs2*ga.z; lg[3]+=xs2*ga.w;
    lg[4]+=xs2*gb.x; lg[5]+=xs2*gb.y; lg[6]+=xs2*gb.z; lg[7]+=xs2*gb.w;
    ga = gp[6]; gb = gp[7];
    lg[0]+=xs3*ga.x; lg[1]+=xs3*ga.y; lg[2]+=xs3*ga.z; lg[3]+=xs3*ga.w;
    lg[4]+=xs3*gb.x; lg[5]+=xs3*gb.y; lg[6]+=xs3*gb.z; lg[7]+=xs3*gb.w;
  }
  #pragma unroll
  for (int off = 32; off; off >>= 1){
    ssq += __shfl_xor(ssq, off, 64);
    #pragma unroll
    for (int e2 = 0; e2 < 8; ++e2) lg[e2] += __shfl_xor(lg[e2], off, 64);
  }
  if (l == 0){
    float c = rsqrtf(ssq * (1.0f/DM) + 1e-6f) * 0.022097086912079608f; // rms * D^-0.5
    float mx = -1e30f;
    #pragma unroll
    for (int e2 = 0; e2 < 8; ++e2){ lg[e2] *= c; mx = fmaxf(mx, lg[e2]); }
    float l0 = lg[0]; int i0 = 0;
    #pragma unroll
    for (int e2 = 1; e2 < 8; ++e2) if (lg[e2] > l0){ l0 = lg[e2]; i0 = e2; }
    int i1 = (i0 == 0) ? 1 : 0; float l1 = (i0 == 0) ? lg[1] : lg[0];
    #pragma unroll
    for (int e2 = 0; e2 < 8; ++e2){ if (e2 != i0 && lg[e2] > l1){ l1 = lg[e2]; i1 = e2; } }
    float p0 = expf(l0 - mx), p1 = expf(l1 - mx);
    float sw = fmaxf(p0 + p1, 1e-12f);
    float w0 = p0 / sw, w1 = p1 / sw;
    int s0 = atomicAdd(&cnt[i0], 1);
    toklist[i0 * NTOK + s0] = n;
    slotw[i0 * NTOK + s0] = w0 * pes[i0];
    tok2slot[2 * n] = (i0 << 16) | s0;
    int s1 = atomicAdd(&cnt[i1], 1);
    toklist[i1 * NTOK + s1] = n;
    slotw[i1 * NTOK + s1] = w1 * pes[i1];
    tok2slot[2 * n + 1] = (i1 << 16) | s1;
  }
}

__global__ void scan_kernel(const int* __restrict__ cnt, int* __restrict__ basep){
  if (threadIdx.x == 0){
    int a = 0;
    for (int e = 0; e < NE; ++e){ basep[e] = a; a += cnt[e]; }
  }
}

// ---------------- weight convert + transpose: W fp32 [2048 k][ncols n] -> Wt bf16 [ncols n][2048 k]
__global__ __launch_bounds__(256) void conv_transpose_kernel(
    const float* __restrict__ W, unsigned short* __restrict__ Wt, int ncols)
{
  const int z = blockIdx.z;
  const float* src = W + (size_t)z * 2048 * ncols;
  unsigned short* dst = Wt + (size_t)z * ncols * 2048;
  const int n0 = blockIdx.x * 64, k0 = blockIdx.y * 64;
  __shared__ __align__(16) unsigned short t[64][72];
  const int tid = threadIdx.x;
  const int kl = tid >> 4;
  const int nl = (tid & 15) * 4;
  #pragma unroll
  for (int q = 0; q < 4; ++q){
    int k = kl + q * 16;
    float4 v = *(const float4*)(src + (size_t)(k0 + k) * ncols + n0 + nl);
    t[nl+0][k] = bf16bits(v.x);
    t[nl+1][k] = bf16bits(v.y);
    t[nl+2][k] = bf16bits(v.z);
    t[nl+3][k] = bf16bits(v.w);
  }
  __syncthreads();
  const int nr = tid >> 3;
  const int k8 = (tid & 7) * 8;
  #pragma unroll
  for (int q = 0; q < 2; ++q){
    int n = nr + q * 32;
    u32x4 v = *(const u32x4*)&t[n][k8];
    *(u32x4*)(dst + (size_t)(n0 + n) * 2048 + k0 + k8) = v;
  }
}

// ---------------- grouped GEMM, m97 structure: 128-row tiles, BK=64, 4 waves (2x2),
// 32KB LDS single-buffered, global_load_lds both operands, natural fb-fastest block
// order, 4 blocks/CU. bounds MUST be (256,4): acc needs 64 VGPRs; (256,5) spills (R11).
// MODE 0: 64 gate + 64 up cols/block; epilogue gelu(g)*u -> act bf16 (no hh roundtrip).
// MODE 1: K-split x2 (blockIdx.y&1 selects K half, 16 iters); plain bf16 stores of the
//         K-partial to ybuf[ks] -> 2x blocks (two residency rounds, tail amortized),
//         zero atomics; combine_kernel sums.  [gemm1 was 1 round + atomic tail = 392 TF]
// MODE 2: legacy atomic scatter (fallback path only).
template<int MODE>
__global__ __launch_bounds__(256, 4) void moe_gemm(
    const unsigned short* __restrict__ Abuf,   // xbf (MODE0) / act (MODE1/2)
    const unsigned short* __restrict__ Wt,     // bf16 [z][ncols][2048] (group-local)
    unsigned short* __restrict__ act,
    float* __restrict__ out,
    unsigned short* __restrict__ ybuf,         // [ks][8192][2048] bf16 (MODE1)
    const int* __restrict__ cnt,
    const int* __restrict__ basep,
    const int* __restrict__ toklist,
    const float* __restrict__ slotw,
    int e0)
{
  const int z = blockIdx.z, e = e0 + z;
  const int ce = cnt[e];
  int my = blockIdx.y, ks = 0;
  if (MODE == 1){ ks = my & 1; my >>= 1; }
  const int m0 = my * 128;
  if (m0 >= ce) return;
  const int fbi = blockIdx.x;
  const int tid = threadIdx.x;
  const int l = tid & 63;
  const int wv = tid >> 6;          // 0..3
  const int wr = wv >> 1, wc = wv & 1;
  const int baseE = basep[e];
  const size_t ncols = (MODE == 0) ? 4096 : 2048;
  const unsigned short* Wz = Wt + (size_t)z * ncols * 2048;

  __shared__ __align__(16) unsigned short As[128 * BK];   // 16 KiB
  __shared__ __align__(16) unsigned short Bs[128 * BK];   // 16 KiB
  __shared__ unsigned char diagpad[MODE == 0 ? 16 : (MODE == 1 ? 544 : 1056)];
  if (basep[0] == -1) *(volatile unsigned char*)&diagpad[tid & 15] = 1;  // never true

  // staging: chunk c = q*256+tid -> row = q*32 + (tid>>3), phys granule tid&7,
  // logical granule g = (tid&7) ^ (row&7); LDS dst linear (wave-uniform base + lane*16B)
  const unsigned short* asrc[4];
  const unsigned short* bsrc[4];
  #pragma unroll
  for (int q = 0; q < 4; ++q){
    int row = q * 32 + (tid >> 3);
    int g = (tid & 7) ^ (row & 7);
    long rs;
    if (MODE == 0) rs = toklist[e * NTOK + min(m0 + row, ce - 1)];
    else           rs = baseE + min(m0 + row, ce - 1);
    asrc[q] = Abuf + (size_t)rs * 2048 + g * 8;
    int wcol;
    if (MODE == 0) wcol = (row < 64) ? (fbi * 64 + row) : (2048 + fbi * 64 + row - 64);
    else           wcol = fbi * 128 + row;
    bsrc[q] = Wz + (size_t)wcol * 2048 + g * 8;
  }

  f32x4 acc[4][4];
  #pragma unroll
  for (int i = 0; i < 4; ++i)
    #pragma unroll
    for (int j2 = 0; j2 < 4; ++j2)
      acc[i][j2] = (f32x4){0.f, 0.f, 0.f, 0.f};

  const int aoff0 = (wr * 64 + (l & 15)) * BK;
  int boffs[4];
  if (MODE == 0){
    // ni 0,1 = gate cols (Bs 0..63), ni 2,3 = up cols (Bs 64..127); same lane-col pairing
    boffs[0] = (wc * 32 + (l & 15)) * BK;
    boffs[1] = (wc * 32 + 16 + (l & 15)) * BK;
    boffs[2] = (64 + wc * 32 + (l & 15)) * BK;
    boffs[3] = (64 + wc * 32 + 16 + (l & 15)) * BK;
  } else {
    #pragma unroll
    for (int ni = 0; ni < 4; ++ni) boffs[ni] = (wc * 64 + ni * 16 + (l & 15)) * BK;
  }
  const int lsw = l & 7;
  const int lq = l >> 4;

  const int kbeg = (MODE == 1) ? ks * 1024 : 0;
  const int kend = (MODE == 1) ? kbeg + 1024 : 2048;

  #pragma unroll 1
  for (int k0 = kbeg; k0 < kend; k0 += BK){
    if (k0 != kbeg) __syncthreads();
    #pragma unroll
    for (int q = 0; q < 4; ++q)
      load_lds16(asrc[q] + k0, &As[q * 2048 + wv * 512]);
    #pragma unroll
    for (int q = 0; q < 4; ++q)
      load_lds16(bsrc[q] + k0, &Bs[q * 2048 + wv * 512]);
    __syncthreads();
    #pragma unroll
    for (int kk = 0; kk < 2; ++kk){
      const int gsw = ((kk * 4 + lq) ^ lsw) * 8;
      bf16x8 af[4];
      #pragma unroll
      for (int mi = 0; mi < 4; ++mi)
        af[mi] = *(const bf16x8*)&As[aoff0 + mi * 16 * BK + gsw];
      #pragma unroll
      for (int ni = 0; ni < 4; ++ni){
        bf16x8 bfr = *(const bf16x8*)&Bs[boffs[ni] + gsw];
        #pragma unroll
        for (int mi = 0; mi < 4; ++mi)
          acc[mi][ni] = __builtin_amdgcn_mfma_f32_16x16x32_bf16(
              af[mi], bfr, acc[mi][ni], 0, 0, 0);
      }
    }
  }

  const int lq4 = (l >> 4) * 4;
  if (MODE == 0){
    #pragma unroll
    for (int mi = 0; mi < 4; ++mi)
      #pragma unroll
      for (int j2 = 0; j2 < 4; ++j2){
        int s = m0 + wr * 64 + mi * 16 + lq4 + j2;
        if (s < ce){
          size_t rowb = (size_t)(baseE + s) * 2048;
          #pragma unroll
          for (int p = 0; p < 2; ++p){
            float g = acc[mi][p][j2];
            float u = acc[mi][p + 2][j2];
            float a = 0.5f * g * (1.0f + erff(g * 0.70710678118654752f)) * u; // exact gelu*up
            act[rowb + fbi * 64 + wc * 32 + p * 16 + (l & 15)] = bf16bits(a);
          }
        }
      }
  } else if (MODE == 1){
    unsigned short* yb = ybuf + (size_t)ks * (2 * NTOK) * 2048;
    #pragma unroll
    for (int mi = 0; mi < 4; ++mi)
      #pragma unroll
      for (int j2 = 0; j2 < 4; ++j2){
        int s = m0 + wr * 64 + mi * 16 + lq4 + j2;
        if (s < ce){
          unsigned short* yr = yb + (size_t)(baseE + s) * 2048 + fbi * 128 + wc * 64 + (l & 15);
          #pragma unroll
          for (int ni = 0; ni < 4; ++ni)
            yr[ni * 16] = bf16bits(acc[mi][ni][j2]);
        }
      }
  } else {
    #pragma unroll
    for (int mi = 0; mi < 4; ++mi)
      #pragma unroll
      for (int j2 = 0; j2 < 4; ++j2){
        int s = m0 + wr * 64 + mi * 16 + lq4 + j2;
        if (s < ce){
          int tokn = toklist[e * NTOK + s];
          float wgt = slotw[e * NTOK + s];
          float* orow = out + (size_t)tokn * 2048 + fbi * 128 + wc * 64 + (l & 15);
          #pragma unroll
          for (int ni = 0; ni < 4; ++ni)
            atomicAdd(&orow[ni * 16], wgt * acc[mi][ni][j2]);
        }
      }
  }
}

// ---------------- combine: out[n] = sum_k slotw[k] * (y0[slot_k] + y1[slot_k])
__global__ __launch_bounds__(256) void combine_kernel(
    const unsigned short* __restrict__ ybuf, const int* __restrict__ tok2slot,
    const float* __restrict__ slotw, const int* __restrict__ basep,
    float* __restrict__ out)
{
  const int n = blockIdx.x * 4 + (threadIdx.x >> 6);
  const int l = threadIdx.x & 63;
  const size_t KS = (size_t)(2 * NTOK) * 2048;
  int p0 = tok2slot[2 * n], p1 = tok2slot[2 * n + 1];
  int e0 = p0 >> 16, s0 = p0 & 0xffff;
  int e1 = p1 >> 16, s1 = p1 & 0xffff;
  float w0 = slotw[e0 * NTOK + s0], w1 = slotw[e1 * NTOK + s1];
  const unsigned short* ya = ybuf + (size_t)(basep[e0] + s0) * 2048;
  const unsigned short* yb = ybuf + (size_t)(basep[e1] + s1) * 2048;
  float* o = out + (size_t)n * 2048;
  #pragma unroll
  for (int q = 0; q < 4; ++q){
    int c8 = (l + 64 * q) * 8;
    u32x4 a0 = *(const u32x4*)(ya + c8);
    u32x4 a1 = *(const u32x4*)(ya + KS + c8);
    u32x4 b0 = *(const u32x4*)(yb + c8);
    u32x4 b1 = *(const u32x4*)(yb + KS + c8);
    float rr[8];
    #pragma unroll
    for (int i = 0; i < 4; ++i){
      rr[2*i]   = w0 * (bflo(a0[i]) + bflo(a1[i])) + w1 * (bflo(b0[i]) + bflo(b1[i]));
      rr[2*i+1] = w0 * (bfhi(a0[i]) + bfhi(a1[i])) + w1 * (bfhi(b0[i]) + bfhi(b1[i]));
    }
    float4 v0 = {rr[0], rr[1], rr[2], rr[3]};
    float4 v1 = {rr[4], rr[5], rr[6], rr[7]};
    *(float4*)(o + c8) = v0;
    *(float4*)(o + c8 + 4) = v1;
  }
}

extern "C" void kernel_launch(void* const* d_in, const int* in_sizes, int n_in,
                              void* d_out, int out_size, void* d_ws, size_t ws_size,
                              hipStream_t stream)
{
  const float* x   = (const float*)d_in[0];
  const float* rs  = (const float*)d_in[1];
  const float* gw  = (const float*)d_in[2];
  const float* w1  = (const float*)d_in[3];
  const float* w2  = (const float*)d_in[4];
  const float* pes = (const float*)d_in[5];
  float* out = (float*)d_out;

  // ws: cnt | base | toklist(128K) | slotw(128K) | tok2slot(32K) | xbf 16MB | act 32MB |
  //     Wt region 128MB (W2t occupies first 64MB during gemm1; ybuf aliases last 64MB)
  char* ws = (char*)d_ws;
  int*   cnt      = (int*)ws;
  int*   basep    = (int*)(ws + 64);
  int*   toklist  = (int*)(ws + 256);
  float* slotw    = (float*)(ws + 256 + (size_t)NE * NTOK * 4);
  int*   tok2slot = (int*)(ws + 256 + 2 * (size_t)NE * NTOK * 4);
  unsigned short* xbf  = (unsigned short*)(ws + 256 + 2 * (size_t)NE * NTOK * 4 + (size_t)NTOK * 8);
  unsigned short* act  = xbf + (size_t)NTOK * DM;
  unsigned short* wtb  = act + (size_t)2 * NTOK * DM;
  unsigned short* ybuf = wtb + (size_t)NE * 2048 * 2048;   // after W2t (64MB in)

  const size_t fixed = (size_t)((char*)wtb - ws);       // ~48.3 MiB
  const size_t per_e = (size_t)4096 * 2048 * 2;         // 16 MiB (W1; W2 uses half)

  hipMemsetAsync(cnt, 0, 64, stream);
  router_kernel<<<NTOK / 4, 256, 0, stream>>>(x, rs, gw, pes, xbf, cnt, toklist, slotw, tok2slot);
  scan_kernel<<<1, 64, 0, stream>>>(cnt, basep);

  if (ws_size >= fixed + (size_t)NE * per_e){
    // single-pass path (established: ws >= 176.3 MiB): no atomics, no out-memset.
    conv_transpose_kernel<<<dim3(64, 32, NE), 256, 0, stream>>>(w1, wtb, 4096);
    moe_gemm<0><<<dim3(32, 32, NE), 256, 0, stream>>>(
        xbf, wtb, act, out, ybuf, cnt, basep, toklist, slotw, 0);
    conv_transpose_kernel<<<dim3(32, 32, NE), 256, 0, stream>>>(w2, wtb, 2048);
    moe_gemm<1><<<dim3(16, 64, NE), 256, 0, stream>>>(
        act, wtb, act, out, ybuf, cnt, basep, toklist, slotw, 0);
    combine_kernel<<<NTOK / 4, 256, 0, stream>>>(ybuf, tok2slot, slotw, basep, out);
  } else {
    hipMemsetAsync(out, 0, (size_t)out_size * sizeof(float), stream);
    int EG = (int)((ws_size > fixed) ? ((ws_size - fixed) / per_e) : 0);
    if (EG < 1) EG = 1;
    if (EG > NE) EG = NE;
    for (int g = 0; g < NE; g += EG){
      int gg = min(EG, NE - g);
      conv_transpose_kernel<<<dim3(64, 32, gg), 256, 0, stream>>>(
          w1 + (size_t)g * 2048 * 4096, wtb, 4096);
      moe_gemm<0><<<dim3(32, 32, gg), 256, 0, stream>>>(
          xbf, wtb, act, out, ybuf, cnt, basep, toklist, slotw, g);
    }
    for (int g = 0; g < NE; g += EG){
      int gg = min(EG, NE - g);
      conv_transpose_kernel<<<dim3(32, 32, gg), 256, 0, stream>>>(
          w2 + (size_t)g * 2048 * 2048, wtb, 2048);
      moe_gemm<2><<<dim3(16, 32, gg), 256, 0, stream>>>(
          act, wtb, act, out, ybuf, cnt, basep, toklist, slotw, g);
    }
  }
}